// Round 15
// baseline (365.436 us; speedup 1.0000x reference)
//
#include <hip/hip_runtime.h>
#include <math.h>

#define NN 50000
#define FEAT 32
#define HID 256
#define NGRAPH 64
#define CAP 48

typedef __attribute__((ext_vector_type(8))) short bfrag;           // 8 bf16 (4 VGPRs)
typedef __attribute__((ext_vector_type(8))) unsigned short u16x8;  // 8 indices
typedef __attribute__((ext_vector_type(4))) float f32x4;           // MFMA accumulator

__device__ __forceinline__ float bf2f(unsigned short u) {
    union { unsigned int i; float f; } v; v.i = ((unsigned int)u) << 16; return v.f;
}
__device__ __forceinline__ unsigned short f2bf(float f) {
    union { float f; unsigned int i; } v; v.f = f;
    unsigned int r = v.i + 0x7fffu + ((v.i >> 16) & 1u);
    return (unsigned short)(r >> 16);
}

// ---------------- weight pack helper ----------------
__device__ __forceinline__ void pack_w(const float* __restrict__ W,
                                       unsigned short* __restrict__ Wp, int K, int o) {
    int j    = o & 7;
    int lane = (o >> 3) & 63;
    int rest = o >> 9;
    int nst  = K >> 5;
    int ks   = rest & (nst - 1);
    int nb   = rest / nst;
    int n = nb * 16 + (lane & 15);
    int k = ks * 32 + (lane >> 4) * 8 + j;
    Wp[o] = f2bf(W[(size_t)k * HID + n]);
}

// ---------------- prep: zero ctr + hist + cursor (must precede setup/histx) ----------------
__global__ void k_prep(float4* __restrict__ zp, int n16) {
    int i = blockIdx.x * blockDim.x + threadIdx.x;
    if (i < n16) zp[i] = make_float4(0.f, 0.f, 0.f, 0.f);
}

// ---------------- setup: CSR scatter + graph bounds + weight packs + zero pooled ----------------
__global__ void k_setup(const int* __restrict__ src, const int* __restrict__ dst,
                        const int* __restrict__ batch,
                        const float* __restrict__ W1, const float* __restrict__ W2,
                        int* __restrict__ counter, unsigned short* __restrict__ csr,
                        int* __restrict__ starts, float* __restrict__ pooled,
                        unsigned short* __restrict__ W1p, unsigned short* __restrict__ W2p,
                        int E, int N) {
    int e = blockIdx.x * blockDim.x + threadIdx.x;
    if (e < E) {
        int d = dst[e];
        int p = atomicAdd(&counter[d], 1);
        if (p < CAP) csr[(size_t)d * CAP + p] = (unsigned short)src[e];
    }
    if (e < N) {
        int b = batch[e];
        int prev = (e == 0) ? -1 : batch[e - 1];
        if (b != prev) {
            for (int g = prev + 1; g <= b; ++g) starts[g] = e;
        }
        if (e == N - 1) {
            for (int g = b + 1; g <= NGRAPH; ++g) starts[g] = N;
        }
    }
    if (e < FEAT * HID) pack_w(W1, W1p, FEAT, e);
    int o2 = e - FEAT * HID;
    if (o2 >= 0 && o2 < HID * HID) pack_w(W2, W2p, HID, o2);
    if (e < NGRAPH * HID) pooled[e] = 0.f;   // consumed only by k_mmfp (later)
}

// ---------------- histx: degree histogram + xbf = bf16(x * dis) ----------------
// 8 nodes/block x 32 lanes. Runs AFTER setup (degrees final).
__global__ void k_histx(const float* __restrict__ x, const int* __restrict__ cnt,
                        unsigned short* __restrict__ xbf, int* __restrict__ hist, int N) {
    __shared__ int lh[49];
    if (threadIdx.x < 49) lh[threadIdx.x] = 0;
    __syncthreads();
    int node = blockIdx.x * 8 + (threadIdx.x >> 5);
    int col = threadIdx.x & 31;
    if (node < N) {
        int ecnt = cnt[node];
        float dn = rsqrtf((float)(ecnt + 1));
        xbf[(size_t)node * FEAT + col] = f2bf(x[(size_t)node * FEAT + col] * dn);
        if (col == 0) {
            int e = ecnt > CAP ? CAP : ecnt;
            atomicAdd(&lh[e], 1);
        }
    }
    __syncthreads();
    if (threadIdx.x < 49 && lh[threadIdx.x]) atomicAdd(&hist[threadIdx.x], lh[threadIdx.x]);
}

// ---------------- perm: counting-sort nodes by (capped) degree ----------------
__global__ void k_perm(const int* __restrict__ cnt, const int* __restrict__ hist,
                       int* __restrict__ cursor, int* __restrict__ perm, int N) {
    __shared__ int pref[49];
    if (threadIdx.x == 0) {
        int s = 0;
        for (int b = 0; b < 49; ++b) { pref[b] = s; s += hist[b]; }
    }
    __syncthreads();
    int n = blockIdx.x * blockDim.x + threadIdx.x;
    if (n < N) {
        int e = cnt[n]; if (e > CAP) e = CAP;
        int r = atomicAdd(&cursor[e], 1);
        perm[pref[e] + r] = n;
    }
}

// ---------------- aggregate x' (pre-scaled bf16), degree-sorted order ----------------
__global__ void k_aggx(const unsigned short* __restrict__ xbf, const int* __restrict__ cnt,
                       const unsigned short* __restrict__ csr, const int* __restrict__ perm,
                       unsigned short* __restrict__ out, int N) {
    int slot = blockIdx.x * 8 + (threadIdx.x >> 5);
    if (slot >= N) return;
    int node = perm[slot];
    int col = threadIdx.x & 31;
    int ecnt = cnt[node];
    float dn = rsqrtf((float)(ecnt + 1));
    int e = ecnt > CAP ? CAP : ecnt;
    const unsigned short* lst = &csr[(size_t)node * CAP];

    float acc = bf2f(xbf[(size_t)node * FEAT + col]);   // self (pre-scaled)
    int i = 0;
    for (; i + 8 <= e; i += 8) {
        u16x8 s = *(const u16x8*)&lst[i];
        float vs[8];
#pragma unroll
        for (int j = 0; j < 8; ++j) vs[j] = bf2f(xbf[(size_t)s[j] * FEAT + col]);
        acc += ((vs[0] + vs[1]) + (vs[2] + vs[3])) + ((vs[4] + vs[5]) + (vs[6] + vs[7]));
    }
    for (; i + 4 <= e; i += 4) {
        float v0 = bf2f(xbf[(size_t)lst[i]     * FEAT + col]);
        float v1 = bf2f(xbf[(size_t)lst[i + 1] * FEAT + col]);
        float v2 = bf2f(xbf[(size_t)lst[i + 2] * FEAT + col]);
        float v3 = bf2f(xbf[(size_t)lst[i + 3] * FEAT + col]);
        acc += (v0 + v1) + (v2 + v3);
    }
    for (; i < e; ++i) acc += bf2f(xbf[(size_t)lst[i] * FEAT + col]);
    out[(size_t)node * FEAT + col] = f2bf(acc * dn);
}

// ---------------- aggregate h1, panel-major + XCD affinity + degree-sorted ----------------
// h/out: [8][N][32] bf16; panel = blockIdx&7 (3.2MB panel per XCD L2). No barriers.
__global__ void k_aggh(const unsigned short* __restrict__ hp, const int* __restrict__ cnt,
                       const unsigned short* __restrict__ csr, const int* __restrict__ perm,
                       unsigned short* __restrict__ outp, int N) {
    int panel = blockIdx.x & 7;
    int slot = (blockIdx.x >> 3) * 64 + (threadIdx.x >> 2);
    if (slot >= N) return;
    int node = perm[slot];
    int c0 = (threadIdx.x & 3) * 8;
    const unsigned short* h = hp + (size_t)panel * N * 32;
    unsigned short* out = outp + (size_t)panel * N * 32;

    int ecnt = cnt[node];
    float dn = rsqrtf((float)(ecnt + 1));
    int e = ecnt > CAP ? CAP : ecnt;
    const unsigned short* lst = &csr[(size_t)node * CAP];

    bfrag sv = *(const bfrag*)&h[(size_t)node * 32 + c0];   // self (pre-scaled by dis)
    float a[8];
#pragma unroll
    for (int j = 0; j < 8; ++j) a[j] = bf2f((unsigned short)sv[j]);

    int i = 0;
    for (; i + 8 <= e; i += 8) {
        u16x8 s = *(const u16x8*)&lst[i];
        bfrag w0 = *(const bfrag*)&h[(size_t)s[0] * 32 + c0];
        bfrag w1 = *(const bfrag*)&h[(size_t)s[1] * 32 + c0];
        bfrag w2 = *(const bfrag*)&h[(size_t)s[2] * 32 + c0];
        bfrag w3 = *(const bfrag*)&h[(size_t)s[3] * 32 + c0];
        bfrag w4 = *(const bfrag*)&h[(size_t)s[4] * 32 + c0];
        bfrag w5 = *(const bfrag*)&h[(size_t)s[5] * 32 + c0];
        bfrag w6 = *(const bfrag*)&h[(size_t)s[6] * 32 + c0];
        bfrag w7 = *(const bfrag*)&h[(size_t)s[7] * 32 + c0];
#pragma unroll
        for (int j = 0; j < 8; ++j) {
            a[j] += ((bf2f((unsigned short)w0[j]) + bf2f((unsigned short)w1[j]))
                   + (bf2f((unsigned short)w2[j]) + bf2f((unsigned short)w3[j])))
                  + ((bf2f((unsigned short)w4[j]) + bf2f((unsigned short)w5[j]))
                   + (bf2f((unsigned short)w6[j]) + bf2f((unsigned short)w7[j])));
        }
    }
    for (; i + 4 <= e; i += 4) {
        bfrag w0 = *(const bfrag*)&h[(size_t)lst[i]     * 32 + c0];
        bfrag w1 = *(const bfrag*)&h[(size_t)lst[i + 1] * 32 + c0];
        bfrag w2 = *(const bfrag*)&h[(size_t)lst[i + 2] * 32 + c0];
        bfrag w3 = *(const bfrag*)&h[(size_t)lst[i + 3] * 32 + c0];
#pragma unroll
        for (int j = 0; j < 8; ++j)
            a[j] += (bf2f((unsigned short)w0[j]) + bf2f((unsigned short)w1[j]))
                  + (bf2f((unsigned short)w2[j]) + bf2f((unsigned short)w3[j]));
    }
    for (; i < e; ++i) {
        bfrag w = *(const bfrag*)&h[(size_t)lst[i] * 32 + c0];
#pragma unroll
        for (int j = 0; j < 8; ++j) a[j] += bf2f((unsigned short)w[j]);
    }
    bfrag o;
#pragma unroll
    for (int j = 0; j < 8; ++j) o[j] = (short)f2bf(a[j] * dn);
    *(bfrag*)&out[(size_t)node * 32 + c0] = o;
}

// ---------------- bf16 MFMA GEMM (layer 1, K=32): h1 = dis * relu(A @ W1 + b1) ----------------
// Output h1 written PANEL-MAJOR [8][M][32].
__global__ __launch_bounds__(256, 4)
void k_mmf(const unsigned short* __restrict__ A, const unsigned short* __restrict__ Wp,
           const float* __restrict__ bias, const int* __restrict__ cnt,
           unsigned short* __restrict__ C, int M) {
    __shared__ unsigned short lds[64 * 264];
    const int K = FEAT;
    int tid  = threadIdx.x;
    int lane = tid & 63;
    int wid  = tid >> 6;
    int l15  = lane & 15;
    int lq   = lane >> 4;
    int row0 = blockIdx.x * 64;

    const int P = K + 8;   // 40
    {
        int flat = tid * 8;
        int row = flat >> 5;
        int col = flat & 31;
        bfrag v = {0, 0, 0, 0, 0, 0, 0, 0};
        int gr = row0 + row;
        if (gr < M) v = *(const bfrag*)&A[(size_t)gr * K + col];
        *(bfrag*)&lds[row * P + col] = v;
    }
    __syncthreads();

    f32x4 acc[4][4];
#pragma unroll
    for (int mi = 0; mi < 4; ++mi)
#pragma unroll
        for (int ni = 0; ni < 4; ++ni) acc[mi][ni] = (f32x4){0.f, 0.f, 0.f, 0.f};

    bfrag fb[4];
#pragma unroll
    for (int ni = 0; ni < 4; ++ni) {
        size_t off = (((size_t)(wid * 4 + ni)) * 64 + lane) * 8;
        fb[ni] = *(const bfrag*)&Wp[off];
    }
    bfrag fa[4];
#pragma unroll
    for (int mi = 0; mi < 4; ++mi)
        fa[mi] = *(const bfrag*)&lds[(mi * 16 + l15) * P + lq * 8];
#pragma unroll
    for (int mi = 0; mi < 4; ++mi)
#pragma unroll
        for (int ni = 0; ni < 4; ++ni)
            acc[mi][ni] = __builtin_amdgcn_mfma_f32_16x16x32_bf16(fb[ni], fa[mi], acc[mi][ni], 0, 0, 0);
    // D^T: lane&15 -> M-row (mi*16+l15); (lane>>4)*4+reg -> N-col ((wid*4+ni)*16+lq*4+reg)

    float4 bv[4];
#pragma unroll
    for (int ni = 0; ni < 4; ++ni)
        bv[ni] = *(const float4*)&bias[(wid * 4 + ni) * 16 + lq * 4];
    float sv[4];
#pragma unroll
    for (int mi = 0; mi < 4; ++mi) {
        int gr = row0 + mi * 16 + l15;
        sv[mi] = (gr < M) ? rsqrtf((float)(cnt[gr] + 1)) : 0.f;
    }

    __syncthreads();
#pragma unroll
    for (int mi = 0; mi < 4; ++mi) {
#pragma unroll
        for (int ni = 0; ni < 4; ++ni) {
            const float* bp = (const float*)&bv[ni];
            ushort4 o;
            o.x = f2bf(fmaxf(acc[mi][ni][0] + bp[0], 0.f) * sv[mi]);
            o.y = f2bf(fmaxf(acc[mi][ni][1] + bp[1], 0.f) * sv[mi]);
            o.z = f2bf(fmaxf(acc[mi][ni][2] + bp[2], 0.f) * sv[mi]);
            o.w = f2bf(fmaxf(acc[mi][ni][3] + bp[3], 0.f) * sv[mi]);
            *(ushort4*)&lds[(mi * 16 + l15) * 264 + (wid * 4 + ni) * 16 + lq * 4] = o;
        }
    }
    __syncthreads();

#pragma unroll
    for (int i = 0; i < 8; ++i) {
        int F = (i * 256 + tid) * 8;
        int row = F >> 8;
        int col = F & 255;
        int gr = row0 + row;
        if (gr < M) {
            bfrag v = *(const bfrag*)&lds[row * 264 + col];
            *(bfrag*)&C[((size_t)(col >> 5) * M + gr) * 32 + (col & 31)] = v;
        }
    }
}

// ---------------- layer-2 GEMM (A panel-major) fused with mean-pool ----------------
__global__ __launch_bounds__(256, 4)
void k_mmfp(const unsigned short* __restrict__ A, const unsigned short* __restrict__ Wp,
            const float* __restrict__ bias, const int* __restrict__ batch,
            float* __restrict__ pooled, int M) {
    __shared__ unsigned short lds[64 * 264];
    __shared__ int bshare[64];
    const int K = HID;
    int tid  = threadIdx.x;
    int lane = tid & 63;
    int wid  = tid >> 6;
    int l15  = lane & 15;
    int lq   = lane >> 4;
    int row0 = blockIdx.x * 64;

    if (tid < 64) {
        int gr = row0 + tid;
        bshare[tid] = (gr < M) ? batch[gr] : -1;
    }

    const int P = K + 8;
    for (int it = 0; it < 8; ++it) {
        int flat = (it * 256 + tid) * 8;
        int row = flat >> 8;
        int col = flat & 255;
        bfrag v = {0, 0, 0, 0, 0, 0, 0, 0};
        int gr = row0 + row;
        if (gr < M) v = *(const bfrag*)&A[((size_t)(col >> 5) * M + gr) * 32 + (col & 31)];
        *(bfrag*)&lds[row * P + col] = v;
    }
    __syncthreads();

    f32x4 acc[4][4];
#pragma unroll
    for (int mi = 0; mi < 4; ++mi)
#pragma unroll
        for (int ni = 0; ni < 4; ++ni) acc[mi][ni] = (f32x4){0.f, 0.f, 0.f, 0.f};

    for (int ks = 0; ks < 8; ++ks) {
        bfrag fb[4];
#pragma unroll
        for (int ni = 0; ni < 4; ++ni) {
            size_t off = (((size_t)(wid * 4 + ni) * 8 + ks) * 64 + lane) * 8;
            fb[ni] = *(const bfrag*)&Wp[off];
        }
        bfrag fa[4];
        int koff = ks * 32 + lq * 8;
#pragma unroll
        for (int mi = 0; mi < 4; ++mi)
            fa[mi] = *(const bfrag*)&lds[(mi * 16 + l15) * P + koff];
#pragma unroll
        for (int mi = 0; mi < 4; ++mi)
#pragma unroll
            for (int ni = 0; ni < 4; ++ni)
                acc[mi][ni] = __builtin_amdgcn_mfma_f32_16x16x32_bf16(fb[ni], fa[mi], acc[mi][ni], 0, 0, 0);
    }

    float4 bv[4];
#pragma unroll
    for (int ni = 0; ni < 4; ++ni)
        bv[ni] = *(const float4*)&bias[(wid * 4 + ni) * 16 + lq * 4];

    __syncthreads();
#pragma unroll
    for (int mi = 0; mi < 4; ++mi) {
#pragma unroll
        for (int ni = 0; ni < 4; ++ni) {
            const float* bp = (const float*)&bv[ni];
            ushort4 o;
            o.x = f2bf(fmaxf(acc[mi][ni][0] + bp[0], 0.f));
            o.y = f2bf(fmaxf(acc[mi][ni][1] + bp[1], 0.f));
            o.z = f2bf(fmaxf(acc[mi][ni][2] + bp[2], 0.f));
            o.w = f2bf(fmaxf(acc[mi][ni][3] + bp[3], 0.f));
            *(ushort4*)&lds[(mi * 16 + l15) * 264 + (wid * 4 + ni) * 16 + lq * 4] = o;
        }
    }
    __syncthreads();

    int c = tid;
    float pacc = 0.f;
    int cur = bshare[0];
    for (int r = 0; r < 64; ++r) {
        int g = bshare[r];
        if (g != cur) {
            if (cur >= 0) atomicAdd(&pooled[(size_t)cur * HID + c], pacc);
            pacc = 0.f; cur = g;
        }
        pacc += bf2f(lds[r * 264 + c]);
    }
    if (cur >= 0) atomicAdd(&pooled[(size_t)cur * HID + c], pacc);
}

// ---------------- head ----------------
__global__ void k_head(const float* __restrict__ pooled, const int* __restrict__ starts,
                       const float* __restrict__ Wf, const float* __restrict__ bf,
                       float* __restrict__ out) {
    int t = blockIdx.x * blockDim.x + threadIdx.x;
    if (t >= NGRAPH * 12) return;
    int g = t / 12, j = t % 12;
    float cntf = (float)(starts[g + 1] - starts[g]);
    float inv = 1.f / fmaxf(cntf, 1.f);
    float s = 0.f;
    for (int k = 0; k < HID; ++k) s += pooled[(size_t)g * HID + k] * Wf[k * 12 + j];
    s = s * inv + bf[j];
    if (j < 6) {
        out[g * 6 + j] = s;
    } else {
        float ls = fminf(fmaxf(s, -20.f), 2.f);
        out[NGRAPH * 6 + g * 6 + (j - 6)] = expf(ls);
    }
}

// ---------------- launch ----------------
extern "C" void kernel_launch(void* const* d_in, const int* in_sizes, int n_in,
                              void* d_out, int out_size, void* d_ws, size_t ws_size,
                              hipStream_t stream) {
    const float* x     = (const float*)d_in[0];
    const int*   ei    = (const int*)d_in[1];
    const int*   batch = (const int*)d_in[2];
    const float* W1    = (const float*)d_in[3];
    const float* b1    = (const float*)d_in[4];
    const float* W2    = (const float*)d_in[5];
    const float* b2    = (const float*)d_in[6];
    const float* Wf    = (const float*)d_in[7];
    const float* bfv   = (const float*)d_in[8];
    float* out = (float*)d_out;

    const int E = in_sizes[1] / 2;
    const int N = in_sizes[2];
    const int* srcp = ei;
    const int* dstp = ei + E;

    // workspace layout
    char* ws = (char*)d_ws;
    const size_t OFF_CTR    = 0;            // int[NN]              -> 200192 (zeroed by k_prep)
    const size_t OFF_HIST   = 200192;       // int[49] (pad 64)     -> 200448 (zeroed by k_prep)
    const size_t OFF_CURSOR = 200448;       // int[49] (pad 64)     -> 200704 (zeroed by k_prep)
    const size_t ZERO_BYTES = 200704;
    const size_t OFF_POOLED = 200704;       // f32[64*256]          -> 266240 (zeroed by k_setup)
    const size_t OFF_STARTS = 266240;       // int[65]              -> 266752
    const size_t OFF_W1P    = 266752;       // bf16[32*256]         -> 283136
    const size_t OFF_W2P    = 283136;       // bf16[256*256]        -> 414208
    const size_t OFF_PERM   = 414208;       // int[NN]              -> 614400 (pad)
    const size_t OFF_CSR    = 614400;       // u16[NN*48]  4.8MB    -> 5414400
    const size_t OFF_XBF    = 5414400;      // bf16[NN*32] 3.2MB    -> 8614400
    const size_t OFF_AGGX   = 8614400;      // bf16[NN*32] 3.2MB    -> 11814400
    const size_t OFF_H1     = 11814400;     // bf16[8][NN][32]      -> 37414400
    const size_t OFF_G      = 37414400;     // bf16[8][NN][32]      -> 63014400

    int*            ctr    = (int*)(ws + OFF_CTR);
    int*            hist   = (int*)(ws + OFF_HIST);
    int*            cursor = (int*)(ws + OFF_CURSOR);
    float*          pooled = (float*)(ws + OFF_POOLED);
    int*            starts = (int*)(ws + OFF_STARTS);
    unsigned short* W1p    = (unsigned short*)(ws + OFF_W1P);
    unsigned short* W2p    = (unsigned short*)(ws + OFF_W2P);
    int*            perm   = (int*)(ws + OFF_PERM);
    unsigned short* csr    = (unsigned short*)(ws + OFF_CSR);
    unsigned short* xbf    = (unsigned short*)(ws + OFF_XBF);
    unsigned short* aggX   = (unsigned short*)(ws + OFF_AGGX);
    unsigned short* h1     = (unsigned short*)(ws + OFF_H1);
    unsigned short* g      = (unsigned short*)(ws + OFF_G);

    const int T = 256;
    k_prep<<<(ZERO_BYTES / 16 + T - 1) / T, T, 0, stream>>>((float4*)ws, ZERO_BYTES / 16);
    k_setup<<<(E + T - 1) / T, T, 0, stream>>>(srcp, dstp, batch, W1, W2,
                                               ctr, csr, starts, pooled, W1p, W2p, E, N);
    k_histx<<<(N + 7) / 8, T, 0, stream>>>(x, ctr, xbf, hist, N);
    k_perm<<<(N + T - 1) / T, T, 0, stream>>>(ctr, hist, cursor, perm, N);

    // layer 1: aggX = dn*(sum xbf[s] + xbf[d]) ; h1 = dis*relu(aggX @ W1 + b1) [panel-major]
    k_aggx<<<(N + 7) / 8, T, 0, stream>>>(xbf, ctr, csr, perm, aggX, N);
    k_mmf<<<(N + 63) / 64, T, 0, stream>>>(aggX, W1p, b1, ctr, h1, N);

    // layer 2: g = dn*(sum h1[s] + h1[d]) per panel (XCD-affine) ; pooled += segreduce(...)
    k_aggh<<<((N + 63) / 64) * 8, T, 0, stream>>>(h1, ctr, csr, perm, g, N);
    k_mmfp<<<(N + 63) / 64, T, 0, stream>>>(g, W2p, b2, batch, pooled, N);

    // head
    k_head<<<3, T, 0, stream>>>(pooled, starts, Wf, bfv, out);
}

// Round 16
// 198.539 us; speedup vs baseline: 1.8406x; 1.8406x over previous
//
#include <hip/hip_runtime.h>
#include <math.h>

#define NN 50000
#define FEAT 32
#define HID 256
#define NGRAPH 64
#define CAP 48

typedef __attribute__((ext_vector_type(8))) short bfrag;           // 8 bf16 (4 VGPRs)
typedef __attribute__((ext_vector_type(8))) unsigned short u16x8;  // 8 indices
typedef __attribute__((ext_vector_type(4))) float f32x4;           // MFMA accumulator

__device__ __forceinline__ float bf2f(unsigned short u) {
    union { unsigned int i; float f; } v; v.i = ((unsigned int)u) << 16; return v.f;
}
__device__ __forceinline__ unsigned short f2bf(float f) {
    union { float f; unsigned int i; } v; v.f = f;
    unsigned int r = v.i + 0x7fffu + ((v.i >> 16) & 1u);
    return (unsigned short)(r >> 16);
}

// ---------------- weight pack helper ----------------
__device__ __forceinline__ void pack_w(const float* __restrict__ W,
                                       unsigned short* __restrict__ Wp, int K, int o) {
    int j    = o & 7;
    int lane = (o >> 3) & 63;
    int rest = o >> 9;
    int nst  = K >> 5;
    int ks   = rest & (nst - 1);
    int nb   = rest / nst;
    int n = nb * 16 + (lane & 15);
    int k = ks * 32 + (lane >> 4) * 8 + j;
    Wp[o] = f2bf(W[(size_t)k * HID + n]);
}

// ---------------- prep: zero ctr + hist + cursor (must precede setup/histx) ----------------
__global__ void k_prep(float4* __restrict__ zp, int n16) {
    int i = blockIdx.x * blockDim.x + threadIdx.x;
    if (i < n16) zp[i] = make_float4(0.f, 0.f, 0.f, 0.f);
}

// ---------------- setup: CSR scatter + graph bounds + weight packs + zero pooled ----------------
__global__ void k_setup(const int* __restrict__ src, const int* __restrict__ dst,
                        const int* __restrict__ batch,
                        const float* __restrict__ W1, const float* __restrict__ W2,
                        int* __restrict__ counter, unsigned short* __restrict__ csr,
                        int* __restrict__ starts, float* __restrict__ pooled,
                        unsigned short* __restrict__ W1p, unsigned short* __restrict__ W2p,
                        int E, int N) {
    int e = blockIdx.x * blockDim.x + threadIdx.x;
    if (e < E) {
        int d = dst[e];
        int p = atomicAdd(&counter[d], 1);
        if (p < CAP) csr[(size_t)d * CAP + p] = (unsigned short)src[e];
    }
    if (e < N) {
        int b = batch[e];
        int prev = (e == 0) ? -1 : batch[e - 1];
        if (b != prev) {
            for (int g = prev + 1; g <= b; ++g) starts[g] = e;
        }
        if (e == N - 1) {
            for (int g = b + 1; g <= NGRAPH; ++g) starts[g] = N;
        }
    }
    if (e < FEAT * HID) pack_w(W1, W1p, FEAT, e);
    int o2 = e - FEAT * HID;
    if (o2 >= 0 && o2 < HID * HID) pack_w(W2, W2p, HID, o2);
    if (e < NGRAPH * HID) pooled[e] = 0.f;   // consumed only by k_mmfp (later)
}

// ---------------- histx: degree histogram + xbf = bf16(x * dis) ----------------
__global__ void k_histx(const float* __restrict__ x, const int* __restrict__ cnt,
                        unsigned short* __restrict__ xbf, int* __restrict__ hist, int N) {
    __shared__ int lh[49];
    if (threadIdx.x < 49) lh[threadIdx.x] = 0;
    __syncthreads();
    int node = blockIdx.x * 8 + (threadIdx.x >> 5);
    int col = threadIdx.x & 31;
    if (node < N) {
        int ecnt = cnt[node];
        float dn = rsqrtf((float)(ecnt + 1));
        xbf[(size_t)node * FEAT + col] = f2bf(x[(size_t)node * FEAT + col] * dn);
        if (col == 0) {
            int e = ecnt > CAP ? CAP : ecnt;
            atomicAdd(&lh[e], 1);
        }
    }
    __syncthreads();
    if (threadIdx.x < 49 && lh[threadIdx.x]) atomicAdd(&hist[threadIdx.x], lh[threadIdx.x]);
}

// ---------------- perm: counting-sort, BLOCK-AGGREGATED global atomics ----------------
// Per block: LDS rank within (block,bin); ONE global atomic per (block,bin).
__global__ void k_perm(const int* __restrict__ cnt, const int* __restrict__ hist,
                       int* __restrict__ cursor, int* __restrict__ perm, int N) {
    __shared__ int pref[49];
    __shared__ int lh[49];
    __shared__ int gbase[49];
    int tid = threadIdx.x;
    if (tid == 0) {
        int s = 0;
        for (int b = 0; b < 49; ++b) { pref[b] = s; s += hist[b]; }
    }
    if (tid < 49) lh[tid] = 0;
    __syncthreads();
    int n = blockIdx.x * blockDim.x + tid;
    int bin = -1, lrank = 0;
    if (n < N) {
        bin = cnt[n]; if (bin > CAP) bin = CAP;
        lrank = atomicAdd(&lh[bin], 1);           // block-local rank (LDS atomic)
    }
    __syncthreads();
    if (tid < 49 && lh[tid]) gbase[tid] = atomicAdd(&cursor[tid], lh[tid]);  // 1/(block,bin)
    __syncthreads();
    if (n < N) perm[pref[bin] + gbase[bin] + lrank] = n;
}

// ---------------- aggregate x' (pre-scaled bf16), degree-sorted order ----------------
__global__ void k_aggx(const unsigned short* __restrict__ xbf, const int* __restrict__ cnt,
                       const unsigned short* __restrict__ csr, const int* __restrict__ perm,
                       unsigned short* __restrict__ out, int N) {
    int slot = blockIdx.x * 8 + (threadIdx.x >> 5);
    if (slot >= N) return;
    int node = perm[slot];
    int col = threadIdx.x & 31;
    int ecnt = cnt[node];
    float dn = rsqrtf((float)(ecnt + 1));
    int e = ecnt > CAP ? CAP : ecnt;
    const unsigned short* lst = &csr[(size_t)node * CAP];

    float acc = bf2f(xbf[(size_t)node * FEAT + col]);   // self (pre-scaled)
    int i = 0;
    for (; i + 8 <= e; i += 8) {
        u16x8 s = *(const u16x8*)&lst[i];
        float vs[8];
#pragma unroll
        for (int j = 0; j < 8; ++j) vs[j] = bf2f(xbf[(size_t)s[j] * FEAT + col]);
        acc += ((vs[0] + vs[1]) + (vs[2] + vs[3])) + ((vs[4] + vs[5]) + (vs[6] + vs[7]));
    }
    for (; i + 4 <= e; i += 4) {
        float v0 = bf2f(xbf[(size_t)lst[i]     * FEAT + col]);
        float v1 = bf2f(xbf[(size_t)lst[i + 1] * FEAT + col]);
        float v2 = bf2f(xbf[(size_t)lst[i + 2] * FEAT + col]);
        float v3 = bf2f(xbf[(size_t)lst[i + 3] * FEAT + col]);
        acc += (v0 + v1) + (v2 + v3);
    }
    for (; i < e; ++i) acc += bf2f(xbf[(size_t)lst[i] * FEAT + col]);
    out[(size_t)node * FEAT + col] = f2bf(acc * dn);
}

// ---------------- aggregate h1, panel-major + XCD affinity + degree-sorted ----------------
__global__ void k_aggh(const unsigned short* __restrict__ hp, const int* __restrict__ cnt,
                       const unsigned short* __restrict__ csr, const int* __restrict__ perm,
                       unsigned short* __restrict__ outp, int N) {
    int panel = blockIdx.x & 7;
    int slot = (blockIdx.x >> 3) * 64 + (threadIdx.x >> 2);
    if (slot >= N) return;
    int node = perm[slot];
    int c0 = (threadIdx.x & 3) * 8;
    const unsigned short* h = hp + (size_t)panel * N * 32;
    unsigned short* out = outp + (size_t)panel * N * 32;

    int ecnt = cnt[node];
    float dn = rsqrtf((float)(ecnt + 1));
    int e = ecnt > CAP ? CAP : ecnt;
    const unsigned short* lst = &csr[(size_t)node * CAP];

    bfrag sv = *(const bfrag*)&h[(size_t)node * 32 + c0];   // self (pre-scaled by dis)
    float a[8];
#pragma unroll
    for (int j = 0; j < 8; ++j) a[j] = bf2f((unsigned short)sv[j]);

    int i = 0;
    for (; i + 8 <= e; i += 8) {
        u16x8 s = *(const u16x8*)&lst[i];
        bfrag w0 = *(const bfrag*)&h[(size_t)s[0] * 32 + c0];
        bfrag w1 = *(const bfrag*)&h[(size_t)s[1] * 32 + c0];
        bfrag w2 = *(const bfrag*)&h[(size_t)s[2] * 32 + c0];
        bfrag w3 = *(const bfrag*)&h[(size_t)s[3] * 32 + c0];
        bfrag w4 = *(const bfrag*)&h[(size_t)s[4] * 32 + c0];
        bfrag w5 = *(const bfrag*)&h[(size_t)s[5] * 32 + c0];
        bfrag w6 = *(const bfrag*)&h[(size_t)s[6] * 32 + c0];
        bfrag w7 = *(const bfrag*)&h[(size_t)s[7] * 32 + c0];
#pragma unroll
        for (int j = 0; j < 8; ++j) {
            a[j] += ((bf2f((unsigned short)w0[j]) + bf2f((unsigned short)w1[j]))
                   + (bf2f((unsigned short)w2[j]) + bf2f((unsigned short)w3[j])))
                  + ((bf2f((unsigned short)w4[j]) + bf2f((unsigned short)w5[j]))
                   + (bf2f((unsigned short)w6[j]) + bf2f((unsigned short)w7[j])));
        }
    }
    for (; i + 4 <= e; i += 4) {
        bfrag w0 = *(const bfrag*)&h[(size_t)lst[i]     * 32 + c0];
        bfrag w1 = *(const bfrag*)&h[(size_t)lst[i + 1] * 32 + c0];
        bfrag w2 = *(const bfrag*)&h[(size_t)lst[i + 2] * 32 + c0];
        bfrag w3 = *(const bfrag*)&h[(size_t)lst[i + 3] * 32 + c0];
#pragma unroll
        for (int j = 0; j < 8; ++j)
            a[j] += (bf2f((unsigned short)w0[j]) + bf2f((unsigned short)w1[j]))
                  + (bf2f((unsigned short)w2[j]) + bf2f((unsigned short)w3[j]));
    }
    for (; i < e; ++i) {
        bfrag w = *(const bfrag*)&h[(size_t)lst[i] * 32 + c0];
#pragma unroll
        for (int j = 0; j < 8; ++j) a[j] += bf2f((unsigned short)w[j]);
    }
    bfrag o;
#pragma unroll
    for (int j = 0; j < 8; ++j) o[j] = (short)f2bf(a[j] * dn);
    *(bfrag*)&out[(size_t)node * 32 + c0] = o;
}

// ---------------- bf16 MFMA GEMM (layer 1, K=32): h1 = dis * relu(A @ W1 + b1) ----------------
__global__ __launch_bounds__(256, 4)
void k_mmf(const unsigned short* __restrict__ A, const unsigned short* __restrict__ Wp,
           const float* __restrict__ bias, const int* __restrict__ cnt,
           unsigned short* __restrict__ C, int M) {
    __shared__ unsigned short lds[64 * 264];
    const int K = FEAT;
    int tid  = threadIdx.x;
    int lane = tid & 63;
    int wid  = tid >> 6;
    int l15  = lane & 15;
    int lq   = lane >> 4;
    int row0 = blockIdx.x * 64;

    const int P = K + 8;   // 40
    {
        int flat = tid * 8;
        int row = flat >> 5;
        int col = flat & 31;
        bfrag v = {0, 0, 0, 0, 0, 0, 0, 0};
        int gr = row0 + row;
        if (gr < M) v = *(const bfrag*)&A[(size_t)gr * K + col];
        *(bfrag*)&lds[row * P + col] = v;
    }
    __syncthreads();

    f32x4 acc[4][4];
#pragma unroll
    for (int mi = 0; mi < 4; ++mi)
#pragma unroll
        for (int ni = 0; ni < 4; ++ni) acc[mi][ni] = (f32x4){0.f, 0.f, 0.f, 0.f};

    bfrag fb[4];
#pragma unroll
    for (int ni = 0; ni < 4; ++ni) {
        size_t off = (((size_t)(wid * 4 + ni)) * 64 + lane) * 8;
        fb[ni] = *(const bfrag*)&Wp[off];
    }
    bfrag fa[4];
#pragma unroll
    for (int mi = 0; mi < 4; ++mi)
        fa[mi] = *(const bfrag*)&lds[(mi * 16 + l15) * P + lq * 8];
#pragma unroll
    for (int mi = 0; mi < 4; ++mi)
#pragma unroll
        for (int ni = 0; ni < 4; ++ni)
            acc[mi][ni] = __builtin_amdgcn_mfma_f32_16x16x32_bf16(fb[ni], fa[mi], acc[mi][ni], 0, 0, 0);
    // D^T: lane&15 -> M-row (mi*16+l15); (lane>>4)*4+reg -> N-col ((wid*4+ni)*16+lq*4+reg)

    float4 bv[4];
#pragma unroll
    for (int ni = 0; ni < 4; ++ni)
        bv[ni] = *(const float4*)&bias[(wid * 4 + ni) * 16 + lq * 4];
    float sv[4];
#pragma unroll
    for (int mi = 0; mi < 4; ++mi) {
        int gr = row0 + mi * 16 + l15;
        sv[mi] = (gr < M) ? rsqrtf((float)(cnt[gr] + 1)) : 0.f;
    }

    __syncthreads();
#pragma unroll
    for (int mi = 0; mi < 4; ++mi) {
#pragma unroll
        for (int ni = 0; ni < 4; ++ni) {
            const float* bp = (const float*)&bv[ni];
            ushort4 o;
            o.x = f2bf(fmaxf(acc[mi][ni][0] + bp[0], 0.f) * sv[mi]);
            o.y = f2bf(fmaxf(acc[mi][ni][1] + bp[1], 0.f) * sv[mi]);
            o.z = f2bf(fmaxf(acc[mi][ni][2] + bp[2], 0.f) * sv[mi]);
            o.w = f2bf(fmaxf(acc[mi][ni][3] + bp[3], 0.f) * sv[mi]);
            *(ushort4*)&lds[(mi * 16 + l15) * 264 + (wid * 4 + ni) * 16 + lq * 4] = o;
        }
    }
    __syncthreads();

#pragma unroll
    for (int i = 0; i < 8; ++i) {
        int F = (i * 256 + tid) * 8;
        int row = F >> 8;
        int col = F & 255;
        int gr = row0 + row;
        if (gr < M) {
            bfrag v = *(const bfrag*)&lds[row * 264 + col];
            *(bfrag*)&C[((size_t)(col >> 5) * M + gr) * 32 + (col & 31)] = v;
        }
    }
}

// ---------------- layer-2 GEMM (A panel-major) fused with mean-pool ----------------
__global__ __launch_bounds__(256, 4)
void k_mmfp(const unsigned short* __restrict__ A, const unsigned short* __restrict__ Wp,
            const float* __restrict__ bias, const int* __restrict__ batch,
            float* __restrict__ pooled, int M) {
    __shared__ unsigned short lds[64 * 264];
    __shared__ int bshare[64];
    const int K = HID;
    int tid  = threadIdx.x;
    int lane = tid & 63;
    int wid  = tid >> 6;
    int l15  = lane & 15;
    int lq   = lane >> 4;
    int row0 = blockIdx.x * 64;

    if (tid < 64) {
        int gr = row0 + tid;
        bshare[tid] = (gr < M) ? batch[gr] : -1;
    }

    const int P = K + 8;
    for (int it = 0; it < 8; ++it) {
        int flat = (it * 256 + tid) * 8;
        int row = flat >> 8;
        int col = flat & 255;
        bfrag v = {0, 0, 0, 0, 0, 0, 0, 0};
        int gr = row0 + row;
        if (gr < M) v = *(const bfrag*)&A[((size_t)(col >> 5) * M + gr) * 32 + (col & 31)];
        *(bfrag*)&lds[row * P + col] = v;
    }
    __syncthreads();

    f32x4 acc[4][4];
#pragma unroll
    for (int mi = 0; mi < 4; ++mi)
#pragma unroll
        for (int ni = 0; ni < 4; ++ni) acc[mi][ni] = (f32x4){0.f, 0.f, 0.f, 0.f};

    for (int ks = 0; ks < 8; ++ks) {
        bfrag fb[4];
#pragma unroll
        for (int ni = 0; ni < 4; ++ni) {
            size_t off = (((size_t)(wid * 4 + ni) * 8 + ks) * 64 + lane) * 8;
            fb[ni] = *(const bfrag*)&Wp[off];
        }
        bfrag fa[4];
        int koff = ks * 32 + lq * 8;
#pragma unroll
        for (int mi = 0; mi < 4; ++mi)
            fa[mi] = *(const bfrag*)&lds[(mi * 16 + l15) * P + koff];
#pragma unroll
        for (int mi = 0; mi < 4; ++mi)
#pragma unroll
            for (int ni = 0; ni < 4; ++ni)
                acc[mi][ni] = __builtin_amdgcn_mfma_f32_16x16x32_bf16(fb[ni], fa[mi], acc[mi][ni], 0, 0, 0);
    }

    float4 bv[4];
#pragma unroll
    for (int ni = 0; ni < 4; ++ni)
        bv[ni] = *(const float4*)&bias[(wid * 4 + ni) * 16 + lq * 4];

    __syncthreads();
#pragma unroll
    for (int mi = 0; mi < 4; ++mi) {
#pragma unroll
        for (int ni = 0; ni < 4; ++ni) {
            const float* bp = (const float*)&bv[ni];
            ushort4 o;
            o.x = f2bf(fmaxf(acc[mi][ni][0] + bp[0], 0.f));
            o.y = f2bf(fmaxf(acc[mi][ni][1] + bp[1], 0.f));
            o.z = f2bf(fmaxf(acc[mi][ni][2] + bp[2], 0.f));
            o.w = f2bf(fmaxf(acc[mi][ni][3] + bp[3], 0.f));
            *(ushort4*)&lds[(mi * 16 + l15) * 264 + (wid * 4 + ni) * 16 + lq * 4] = o;
        }
    }
    __syncthreads();

    int c = tid;
    float pacc = 0.f;
    int cur = bshare[0];
    for (int r = 0; r < 64; ++r) {
        int g = bshare[r];
        if (g != cur) {
            if (cur >= 0) atomicAdd(&pooled[(size_t)cur * HID + c], pacc);
            pacc = 0.f; cur = g;
        }
        pacc += bf2f(lds[r * 264 + c]);
    }
    if (cur >= 0) atomicAdd(&pooled[(size_t)cur * HID + c], pacc);
}

// ---------------- head ----------------
__global__ void k_head(const float* __restrict__ pooled, const int* __restrict__ starts,
                       const float* __restrict__ Wf, const float* __restrict__ bf,
                       float* __restrict__ out) {
    int t = blockIdx.x * blockDim.x + threadIdx.x;
    if (t >= NGRAPH * 12) return;
    int g = t / 12, j = t % 12;
    float cntf = (float)(starts[g + 1] - starts[g]);
    float inv = 1.f / fmaxf(cntf, 1.f);
    float s = 0.f;
    for (int k = 0; k < HID; ++k) s += pooled[(size_t)g * HID + k] * Wf[k * 12 + j];
    s = s * inv + bf[j];
    if (j < 6) {
        out[g * 6 + j] = s;
    } else {
        float ls = fminf(fmaxf(s, -20.f), 2.f);
        out[NGRAPH * 6 + g * 6 + (j - 6)] = expf(ls);
    }
}

// ---------------- launch ----------------
extern "C" void kernel_launch(void* const* d_in, const int* in_sizes, int n_in,
                              void* d_out, int out_size, void* d_ws, size_t ws_size,
                              hipStream_t stream) {
    const float* x     = (const float*)d_in[0];
    const int*   ei    = (const int*)d_in[1];
    const int*   batch = (const int*)d_in[2];
    const float* W1    = (const float*)d_in[3];
    const float* b1    = (const float*)d_in[4];
    const float* W2    = (const float*)d_in[5];
    const float* b2    = (const float*)d_in[6];
    const float* Wf    = (const float*)d_in[7];
    const float* bfv   = (const float*)d_in[8];
    float* out = (float*)d_out;

    const int E = in_sizes[1] / 2;
    const int N = in_sizes[2];
    const int* srcp = ei;
    const int* dstp = ei + E;

    // workspace layout
    char* ws = (char*)d_ws;
    const size_t OFF_CTR    = 0;            // int[NN]              -> 200192 (zeroed by k_prep)
    const size_t OFF_HIST   = 200192;       // int[49] (pad 64)     -> 200448 (zeroed by k_prep)
    const size_t OFF_CURSOR = 200448;       // int[49] (pad 64)     -> 200704 (zeroed by k_prep)
    const size_t ZERO_BYTES = 200704;
    const size_t OFF_POOLED = 200704;       // f32[64*256]          -> 266240 (zeroed by k_setup)
    const size_t OFF_STARTS = 266240;       // int[65]              -> 266752
    const size_t OFF_W1P    = 266752;       // bf16[32*256]         -> 283136
    const size_t OFF_W2P    = 283136;       // bf16[256*256]        -> 414208
    const size_t OFF_PERM   = 414208;       // int[NN]              -> 614400 (pad)
    const size_t OFF_CSR    = 614400;       // u16[NN*48]  4.8MB    -> 5414400
    const size_t OFF_XBF    = 5414400;      // bf16[NN*32] 3.2MB    -> 8614400
    const size_t OFF_AGGX   = 8614400;      // bf16[NN*32] 3.2MB    -> 11814400
    const size_t OFF_H1     = 11814400;     // bf16[8][NN][32]      -> 37414400
    const size_t OFF_G      = 37414400;     // bf16[8][NN][32]      -> 63014400

    int*            ctr    = (int*)(ws + OFF_CTR);
    int*            hist   = (int*)(ws + OFF_HIST);
    int*            cursor = (int*)(ws + OFF_CURSOR);
    float*          pooled = (float*)(ws + OFF_POOLED);
    int*            starts = (int*)(ws + OFF_STARTS);
    unsigned short* W1p    = (unsigned short*)(ws + OFF_W1P);
    unsigned short* W2p    = (unsigned short*)(ws + OFF_W2P);
    int*            perm   = (int*)(ws + OFF_PERM);
    unsigned short* csr    = (unsigned short*)(ws + OFF_CSR);
    unsigned short* xbf    = (unsigned short*)(ws + OFF_XBF);
    unsigned short* aggX   = (unsigned short*)(ws + OFF_AGGX);
    unsigned short* h1     = (unsigned short*)(ws + OFF_H1);
    unsigned short* g      = (unsigned short*)(ws + OFF_G);

    const int T = 256;
    k_prep<<<(ZERO_BYTES / 16 + T - 1) / T, T, 0, stream>>>((float4*)ws, ZERO_BYTES / 16);
    k_setup<<<(E + T - 1) / T, T, 0, stream>>>(srcp, dstp, batch, W1, W2,
                                               ctr, csr, starts, pooled, W1p, W2p, E, N);
    k_histx<<<(N + 7) / 8, T, 0, stream>>>(x, ctr, xbf, hist, N);
    k_perm<<<(N + T - 1) / T, T, 0, stream>>>(ctr, hist, cursor, perm, N);

    // layer 1: aggX = dn*(sum xbf[s] + xbf[d]) ; h1 = dis*relu(aggX @ W1 + b1) [panel-major]
    k_aggx<<<(N + 7) / 8, T, 0, stream>>>(xbf, ctr, csr, perm, aggX, N);
    k_mmf<<<(N + 63) / 64, T, 0, stream>>>(aggX, W1p, b1, ctr, h1, N);

    // layer 2: g = dn*(sum h1[s] + h1[d]) per panel (XCD-affine) ; pooled += segreduce(...)
    k_aggh<<<((N + 63) / 64) * 8, T, 0, stream>>>(h1, ctr, csr, perm, g, N);
    k_mmfp<<<(N + 63) / 64, T, 0, stream>>>(g, W2p, b2, batch, pooled, N);

    // head
    k_head<<<3, T, 0, stream>>>(pooled, starts, Wf, bfv, out);
}

// Round 17
// 118.382 us; speedup vs baseline: 3.0869x; 1.6771x over previous
//
#include <hip/hip_runtime.h>
#include <math.h>

#define NN 50000
#define FEAT 32
#define HID 256
#define NGRAPH 64
#define CAP 48

typedef __attribute__((ext_vector_type(8))) short bfrag;           // 8 bf16 (4 VGPRs)
typedef __attribute__((ext_vector_type(8))) unsigned short u16x8;  // 8 indices
typedef __attribute__((ext_vector_type(4))) float f32x4;           // MFMA accumulator

__device__ __forceinline__ float bf2f(unsigned short u) {
    union { unsigned int i; float f; } v; v.i = ((unsigned int)u) << 16; return v.f;
}
__device__ __forceinline__ unsigned short f2bf(float f) {
    union { float f; unsigned int i; } v; v.f = f;
    unsigned int r = v.i + 0x7fffu + ((v.i >> 16) & 1u);
    return (unsigned short)(r >> 16);
}

// ---------------- weight pack helper ----------------
__device__ __forceinline__ void pack_w(const float* __restrict__ W,
                                       unsigned short* __restrict__ Wp, int K, int o) {
    int j    = o & 7;
    int lane = (o >> 3) & 63;
    int rest = o >> 9;
    int nst  = K >> 5;
    int ks   = rest & (nst - 1);
    int nb   = rest / nst;
    int n = nb * 16 + (lane & 15);
    int k = ks * 32 + (lane >> 4) * 8 + j;
    Wp[o] = f2bf(W[(size_t)k * HID + n]);
}

// ---------------- prep: zero ctr only (must precede setup's atomics) ----------------
__global__ void k_prep(float4* __restrict__ zp, int n16) {
    int i = blockIdx.x * blockDim.x + threadIdx.x;
    if (i < n16) zp[i] = make_float4(0.f, 0.f, 0.f, 0.f);
}

// ---------------- setup: CSR scatter + graph bounds + weight packs + zero pooled ----------------
__global__ void k_setup(const int* __restrict__ src, const int* __restrict__ dst,
                        const int* __restrict__ batch,
                        const float* __restrict__ W1, const float* __restrict__ W2,
                        int* __restrict__ counter, unsigned short* __restrict__ csr,
                        int* __restrict__ starts, float* __restrict__ pooled,
                        unsigned short* __restrict__ W1p, unsigned short* __restrict__ W2p,
                        int E, int N) {
    int e = blockIdx.x * blockDim.x + threadIdx.x;
    if (e < E) {
        int d = dst[e];
        int p = atomicAdd(&counter[d], 1);
        if (p < CAP) csr[(size_t)d * CAP + p] = (unsigned short)src[e];
    }
    if (e < N) {
        int b = batch[e];
        int prev = (e == 0) ? -1 : batch[e - 1];
        if (b != prev) {
            for (int g = prev + 1; g <= b; ++g) starts[g] = e;
        }
        if (e == N - 1) {
            for (int g = b + 1; g <= NGRAPH; ++g) starts[g] = N;
        }
    }
    if (e < FEAT * HID) pack_w(W1, W1p, FEAT, e);
    int o2 = e - FEAT * HID;
    if (o2 >= 0 && o2 < HID * HID) pack_w(W2, W2p, HID, o2);
    if (e < NGRAPH * HID) pooled[e] = 0.f;   // consumed only by k_mmfp (later)
}

// ---------------- aggregate layer-1 input: gather raw f32 x, weight rsqrt(cnt+1) ----------------
__global__ void k_aggx(const float* __restrict__ x, const int* __restrict__ cnt,
                       const unsigned short* __restrict__ csr,
                       unsigned short* __restrict__ out, int N) {
    int node = blockIdx.x * 8 + (threadIdx.x >> 5);
    if (node >= N) return;
    int col = threadIdx.x & 31;
    int ecnt = cnt[node];
    float dn = rsqrtf((float)(ecnt + 1));
    int e = ecnt > CAP ? CAP : ecnt;
    const unsigned short* lst = &csr[(size_t)node * CAP];

    float acc = x[(size_t)node * FEAT + col] * dn;
    int i = 0;
    for (; i + 8 <= e; i += 8) {
        u16x8 s = *(const u16x8*)&lst[i];
        float vs[8];
#pragma unroll
        for (int j = 0; j < 8; ++j) {
            int sj = (int)s[j];
            vs[j] = x[(size_t)sj * FEAT + col] * rsqrtf((float)(cnt[sj] + 1));
        }
        acc += ((vs[0] + vs[1]) + (vs[2] + vs[3])) + ((vs[4] + vs[5]) + (vs[6] + vs[7]));
    }
    for (; i + 4 <= e; i += 4) {
        float vs[4];
#pragma unroll
        for (int j = 0; j < 4; ++j) {
            int sj = (int)lst[i + j];
            vs[j] = x[(size_t)sj * FEAT + col] * rsqrtf((float)(cnt[sj] + 1));
        }
        acc += (vs[0] + vs[1]) + (vs[2] + vs[3]);
    }
    for (; i < e; ++i) {
        int sj = (int)lst[i];
        acc += x[(size_t)sj * FEAT + col] * rsqrtf((float)(cnt[sj] + 1));
    }
    out[(size_t)node * FEAT + col] = f2bf(acc * dn);
}

// ---------------- aggregate h1, panel-major: panel = blockIdx&7 (XCD affinity) ----------------
// h/out layout: [8][N][32] bf16; one panel = 3.2MB -> fits one XCD's 4MB L2.
// 256 thr = 64 nodes x 4 lanes; NO barriers — waves retire independently.
__global__ void k_aggh(const unsigned short* __restrict__ hp, const int* __restrict__ cnt,
                       const unsigned short* __restrict__ csr,
                       unsigned short* __restrict__ outp, int N) {
    int panel = blockIdx.x & 7;
    int node = (blockIdx.x >> 3) * 64 + (threadIdx.x >> 2);
    if (node >= N) return;
    int c0 = (threadIdx.x & 3) * 8;
    const unsigned short* h = hp + (size_t)panel * N * 32;
    unsigned short* out = outp + (size_t)panel * N * 32;

    int ecnt = cnt[node];
    float dn = rsqrtf((float)(ecnt + 1));
    int e = ecnt > CAP ? CAP : ecnt;
    const unsigned short* lst = &csr[(size_t)node * CAP];

    bfrag sv = *(const bfrag*)&h[(size_t)node * 32 + c0];   // self (pre-scaled by dis)
    float a[8];
#pragma unroll
    for (int j = 0; j < 8; ++j) a[j] = bf2f((unsigned short)sv[j]);

    int i = 0;
    for (; i + 8 <= e; i += 8) {
        u16x8 s = *(const u16x8*)&lst[i];
        bfrag w0 = *(const bfrag*)&h[(size_t)s[0] * 32 + c0];
        bfrag w1 = *(const bfrag*)&h[(size_t)s[1] * 32 + c0];
        bfrag w2 = *(const bfrag*)&h[(size_t)s[2] * 32 + c0];
        bfrag w3 = *(const bfrag*)&h[(size_t)s[3] * 32 + c0];
        bfrag w4 = *(const bfrag*)&h[(size_t)s[4] * 32 + c0];
        bfrag w5 = *(const bfrag*)&h[(size_t)s[5] * 32 + c0];
        bfrag w6 = *(const bfrag*)&h[(size_t)s[6] * 32 + c0];
        bfrag w7 = *(const bfrag*)&h[(size_t)s[7] * 32 + c0];
#pragma unroll
        for (int j = 0; j < 8; ++j) {
            a[j] += ((bf2f((unsigned short)w0[j]) + bf2f((unsigned short)w1[j]))
                   + (bf2f((unsigned short)w2[j]) + bf2f((unsigned short)w3[j])))
                  + ((bf2f((unsigned short)w4[j]) + bf2f((unsigned short)w5[j]))
                   + (bf2f((unsigned short)w6[j]) + bf2f((unsigned short)w7[j])));
        }
    }
    for (; i + 4 <= e; i += 4) {
        bfrag w0 = *(const bfrag*)&h[(size_t)lst[i]     * 32 + c0];
        bfrag w1 = *(const bfrag*)&h[(size_t)lst[i + 1] * 32 + c0];
        bfrag w2 = *(const bfrag*)&h[(size_t)lst[i + 2] * 32 + c0];
        bfrag w3 = *(const bfrag*)&h[(size_t)lst[i + 3] * 32 + c0];
#pragma unroll
        for (int j = 0; j < 8; ++j)
            a[j] += (bf2f((unsigned short)w0[j]) + bf2f((unsigned short)w1[j]))
                  + (bf2f((unsigned short)w2[j]) + bf2f((unsigned short)w3[j]));
    }
    for (; i < e; ++i) {
        bfrag w = *(const bfrag*)&h[(size_t)lst[i] * 32 + c0];
#pragma unroll
        for (int j = 0; j < 8; ++j) a[j] += bf2f((unsigned short)w[j]);
    }
    bfrag o;
#pragma unroll
    for (int j = 0; j < 8; ++j) o[j] = (short)f2bf(a[j] * dn);
    *(bfrag*)&out[(size_t)node * 32 + c0] = o;
}

// ---------------- bf16 MFMA GEMM (layer 1, K=32): h1 = dis * relu(A @ W1 + b1) ----------------
// Output h1 written PANEL-MAJOR [8][M][32].
__global__ __launch_bounds__(256, 4)
void k_mmf(const unsigned short* __restrict__ A, const unsigned short* __restrict__ Wp,
           const float* __restrict__ bias, const int* __restrict__ cnt,
           unsigned short* __restrict__ C, int M) {
    __shared__ unsigned short lds[64 * 264];
    const int K = FEAT;
    int tid  = threadIdx.x;
    int lane = tid & 63;
    int wid  = tid >> 6;
    int l15  = lane & 15;
    int lq   = lane >> 4;
    int row0 = blockIdx.x * 64;

    const int P = K + 8;   // 40
    {
        int flat = tid * 8;
        int row = flat >> 5;
        int col = flat & 31;
        bfrag v = {0, 0, 0, 0, 0, 0, 0, 0};
        int gr = row0 + row;
        if (gr < M) v = *(const bfrag*)&A[(size_t)gr * K + col];
        *(bfrag*)&lds[row * P + col] = v;
    }
    __syncthreads();

    f32x4 acc[4][4];
#pragma unroll
    for (int mi = 0; mi < 4; ++mi)
#pragma unroll
        for (int ni = 0; ni < 4; ++ni) acc[mi][ni] = (f32x4){0.f, 0.f, 0.f, 0.f};

    bfrag fb[4];
#pragma unroll
    for (int ni = 0; ni < 4; ++ni) {
        size_t off = (((size_t)(wid * 4 + ni)) * 64 + lane) * 8;
        fb[ni] = *(const bfrag*)&Wp[off];
    }
    bfrag fa[4];
#pragma unroll
    for (int mi = 0; mi < 4; ++mi)
        fa[mi] = *(const bfrag*)&lds[(mi * 16 + l15) * P + lq * 8];
#pragma unroll
    for (int mi = 0; mi < 4; ++mi)
#pragma unroll
        for (int ni = 0; ni < 4; ++ni)
            acc[mi][ni] = __builtin_amdgcn_mfma_f32_16x16x32_bf16(fb[ni], fa[mi], acc[mi][ni], 0, 0, 0);
    // D^T: lane&15 -> M-row (mi*16+l15); (lane>>4)*4+reg -> N-col ((wid*4+ni)*16+lq*4+reg)

    float4 bv[4];
#pragma unroll
    for (int ni = 0; ni < 4; ++ni)
        bv[ni] = *(const float4*)&bias[(wid * 4 + ni) * 16 + lq * 4];
    float sv[4];
#pragma unroll
    for (int mi = 0; mi < 4; ++mi) {
        int gr = row0 + mi * 16 + l15;
        sv[mi] = (gr < M) ? rsqrtf((float)(cnt[gr] + 1)) : 0.f;
    }

    __syncthreads();
#pragma unroll
    for (int mi = 0; mi < 4; ++mi) {
#pragma unroll
        for (int ni = 0; ni < 4; ++ni) {
            const float* bp = (const float*)&bv[ni];
            ushort4 o;
            o.x = f2bf(fmaxf(acc[mi][ni][0] + bp[0], 0.f) * sv[mi]);
            o.y = f2bf(fmaxf(acc[mi][ni][1] + bp[1], 0.f) * sv[mi]);
            o.z = f2bf(fmaxf(acc[mi][ni][2] + bp[2], 0.f) * sv[mi]);
            o.w = f2bf(fmaxf(acc[mi][ni][3] + bp[3], 0.f) * sv[mi]);
            *(ushort4*)&lds[(mi * 16 + l15) * 264 + (wid * 4 + ni) * 16 + lq * 4] = o;
        }
    }
    __syncthreads();

#pragma unroll
    for (int i = 0; i < 8; ++i) {
        int F = (i * 256 + tid) * 8;
        int row = F >> 8;
        int col = F & 255;
        int gr = row0 + row;
        if (gr < M) {
            bfrag v = *(const bfrag*)&lds[row * 264 + col];
            *(bfrag*)&C[((size_t)(col >> 5) * M + gr) * 32 + (col & 31)] = v;
        }
    }
}

// ---------------- layer-2 GEMM (A panel-major) fused with mean-pool ----------------
__global__ __launch_bounds__(256, 4)
void k_mmfp(const unsigned short* __restrict__ A, const unsigned short* __restrict__ Wp,
            const float* __restrict__ bias, const int* __restrict__ batch,
            float* __restrict__ pooled, int M) {
    __shared__ unsigned short lds[64 * 264];
    __shared__ int bshare[64];
    const int K = HID;
    int tid  = threadIdx.x;
    int lane = tid & 63;
    int wid  = tid >> 6;
    int l15  = lane & 15;
    int lq   = lane >> 4;
    int row0 = blockIdx.x * 64;

    if (tid < 64) {
        int gr = row0 + tid;
        bshare[tid] = (gr < M) ? batch[gr] : -1;
    }

    const int P = K + 8;
    for (int it = 0; it < 8; ++it) {
        int flat = (it * 256 + tid) * 8;
        int row = flat >> 8;
        int col = flat & 255;
        bfrag v = {0, 0, 0, 0, 0, 0, 0, 0};
        int gr = row0 + row;
        if (gr < M) v = *(const bfrag*)&A[((size_t)(col >> 5) * M + gr) * 32 + (col & 31)];
        *(bfrag*)&lds[row * P + col] = v;
    }
    __syncthreads();

    f32x4 acc[4][4];
#pragma unroll
    for (int mi = 0; mi < 4; ++mi)
#pragma unroll
        for (int ni = 0; ni < 4; ++ni) acc[mi][ni] = (f32x4){0.f, 0.f, 0.f, 0.f};

    for (int ks = 0; ks < 8; ++ks) {
        bfrag fb[4];
#pragma unroll
        for (int ni = 0; ni < 4; ++ni) {
            size_t off = (((size_t)(wid * 4 + ni) * 8 + ks) * 64 + lane) * 8;
            fb[ni] = *(const bfrag*)&Wp[off];
        }
        bfrag fa[4];
        int koff = ks * 32 + lq * 8;
#pragma unroll
        for (int mi = 0; mi < 4; ++mi)
            fa[mi] = *(const bfrag*)&lds[(mi * 16 + l15) * P + koff];
#pragma unroll
        for (int mi = 0; mi < 4; ++mi)
#pragma unroll
            for (int ni = 0; ni < 4; ++ni)
                acc[mi][ni] = __builtin_amdgcn_mfma_f32_16x16x32_bf16(fb[ni], fa[mi], acc[mi][ni], 0, 0, 0);
    }

    float4 bv[4];
#pragma unroll
    for (int ni = 0; ni < 4; ++ni)
        bv[ni] = *(const float4*)&bias[(wid * 4 + ni) * 16 + lq * 4];

    __syncthreads();
#pragma unroll
    for (int mi = 0; mi < 4; ++mi) {
#pragma unroll
        for (int ni = 0; ni < 4; ++ni) {
            const float* bp = (const float*)&bv[ni];
            ushort4 o;
            o.x = f2bf(fmaxf(acc[mi][ni][0] + bp[0], 0.f));
            o.y = f2bf(fmaxf(acc[mi][ni][1] + bp[1], 0.f));
            o.z = f2bf(fmaxf(acc[mi][ni][2] + bp[2], 0.f));
            o.w = f2bf(fmaxf(acc[mi][ni][3] + bp[3], 0.f));
            *(ushort4*)&lds[(mi * 16 + l15) * 264 + (wid * 4 + ni) * 16 + lq * 4] = o;
        }
    }
    __syncthreads();

    int c = tid;
    float pacc = 0.f;
    int cur = bshare[0];
    for (int r = 0; r < 64; ++r) {
        int g = bshare[r];
        if (g != cur) {
            if (cur >= 0) atomicAdd(&pooled[(size_t)cur * HID + c], pacc);
            pacc = 0.f; cur = g;
        }
        pacc += bf2f(lds[r * 264 + c]);
    }
    if (cur >= 0) atomicAdd(&pooled[(size_t)cur * HID + c], pacc);
}

// ---------------- head ----------------
__global__ void k_head(const float* __restrict__ pooled, const int* __restrict__ starts,
                       const float* __restrict__ Wf, const float* __restrict__ bf,
                       float* __restrict__ out) {
    int t = blockIdx.x * blockDim.x + threadIdx.x;
    if (t >= NGRAPH * 12) return;
    int g = t / 12, j = t % 12;
    float cntf = (float)(starts[g + 1] - starts[g]);
    float inv = 1.f / fmaxf(cntf, 1.f);
    float s = 0.f;
    for (int k = 0; k < HID; ++k) s += pooled[(size_t)g * HID + k] * Wf[k * 12 + j];
    s = s * inv + bf[j];
    if (j < 6) {
        out[g * 6 + j] = s;
    } else {
        float ls = fminf(fmaxf(s, -20.f), 2.f);
        out[NGRAPH * 6 + g * 6 + (j - 6)] = expf(ls);
    }
}

// ---------------- launch ----------------
extern "C" void kernel_launch(void* const* d_in, const int* in_sizes, int n_in,
                              void* d_out, int out_size, void* d_ws, size_t ws_size,
                              hipStream_t stream) {
    const float* x     = (const float*)d_in[0];
    const int*   ei    = (const int*)d_in[1];
    const int*   batch = (const int*)d_in[2];
    const float* W1    = (const float*)d_in[3];
    const float* b1    = (const float*)d_in[4];
    const float* W2    = (const float*)d_in[5];
    const float* b2    = (const float*)d_in[6];
    const float* Wf    = (const float*)d_in[7];
    const float* bfv   = (const float*)d_in[8];
    float* out = (float*)d_out;

    const int E = in_sizes[1] / 2;
    const int N = in_sizes[2];
    const int* srcp = ei;
    const int* dstp = ei + E;

    // workspace layout
    char* ws = (char*)d_ws;
    const size_t OFF_CTR    = 0;            // int[NN]              -> 200192 (zeroed by k_prep)
    const size_t OFF_POOLED = 200192;       // f32[64*256]          -> 265728 (zeroed by k_setup)
    const size_t OFF_STARTS = 265728;       // int[65]              -> 266240
    const size_t OFF_W1P    = 266240;       // bf16[32*256]         -> 282624
    const size_t OFF_W2P    = 282624;       // bf16[256*256]        -> 413696
    const size_t OFF_CSR    = 413696;       // u16[NN*48]  4.8MB    -> 5213696
    const size_t OFF_AGGX   = 5213696;      // bf16[NN*32] 3.2MB    -> 8413696
    const size_t OFF_H1     = 8413696;      // bf16[8][NN][32]      -> 34013696
    const size_t OFF_G      = 34013696;     // bf16[8][NN][32]      -> 59613696

    int*            ctr    = (int*)(ws + OFF_CTR);
    float*          pooled = (float*)(ws + OFF_POOLED);
    int*            starts = (int*)(ws + OFF_STARTS);
    unsigned short* W1p    = (unsigned short*)(ws + OFF_W1P);
    unsigned short* W2p    = (unsigned short*)(ws + OFF_W2P);
    unsigned short* csr    = (unsigned short*)(ws + OFF_CSR);
    unsigned short* aggX   = (unsigned short*)(ws + OFF_AGGX);
    unsigned short* h1     = (unsigned short*)(ws + OFF_H1);
    unsigned short* g      = (unsigned short*)(ws + OFF_G);

    const int T = 256;
    k_prep<<<(200192 / 16 + T - 1) / T, T, 0, stream>>>((float4*)ws, 200192 / 16);
    k_setup<<<(E + T - 1) / T, T, 0, stream>>>(srcp, dstp, batch, W1, W2,
                                               ctr, csr, starts, pooled, W1p, W2p, E, N);

    // layer 1: aggX = dn*(sum x[s]*dis_s + x[d]*dn) ; h1 = dis*relu(aggX @ W1 + b1) [panel]
    k_aggx<<<(N + 7) / 8, T, 0, stream>>>(x, ctr, csr, aggX, N);
    k_mmf<<<(N + 63) / 64, T, 0, stream>>>(aggX, W1p, b1, ctr, h1, N);

    // layer 2: g = dn*(sum h1[s] + h1[d]) per panel (XCD-affine) ; pooled += segreduce(...)
    k_aggh<<<((N + 63) / 64) * 8, T, 0, stream>>>(h1, ctr, csr, g, N);
    k_mmfp<<<(N + 63) / 64, T, 0, stream>>>(g, W2p, b2, batch, pooled, N);

    // head
    k_head<<<3, T, 0, stream>>>(pooled, starts, Wf, bfv, out);
}